// Round 1
// baseline (33.699 us; speedup 1.0000x reference)
//
#include <hip/hip_runtime.h>
#include <math.h>

#define D 256
#define EPS 1e-8f

// loss of one row: logits = {pos, n1, n2} / 0.5, CE with label 0
__device__ __forceinline__ float row_loss(float pos, float na, float nb) {
    float l0 = pos + pos;   // /T with T=0.5
    float l1 = na + na;
    float l2 = nb + nb;
    float m  = fmaxf(l0, fmaxf(l1, l2));
    float e  = expf(l0 - m) + expf(l1 - m) + expf(l2 - m);
    return logf(e) - (l0 - m);
}

__global__ __launch_bounds__(256) void ntxent_partial_kernel(
    const float* __restrict__ zis, const float* __restrict__ zjs,
    int n_chunks, float* __restrict__ partial)
{
    const int tid      = blockIdx.x * 256 + threadIdx.x;
    const int lane     = threadIdx.x & 15;          // lane within 16-lane group
    const int group    = tid >> 4;
    const int n_groups = (gridDim.x * 256) >> 4;

    float local = 0.0f;

    for (int c = group; c < n_chunks; c += n_groups) {
        // reps rows: r0 = zj row0, r1 = zj row1, r2 = zi row0, r3 = zi row1
        const float4* zi = (const float4*)(zis + (size_t)c * (2 * D));
        const float4* zj = (const float4*)(zjs + (size_t)c * (2 * D));

        float s00=0.f,s11=0.f,s22=0.f,s33=0.f;
        float s01=0.f,s02=0.f,s03=0.f,s12=0.f,s13=0.f,s23=0.f;
        #pragma unroll
        for (int i = 0; i < 4; ++i) {
            const int idx = lane * 4 + i;           // float4 index within a 64-float4 row
            float4 r0 = zj[idx];
            float4 r1 = zj[64 + idx];
            float4 r2 = zi[idx];
            float4 r3 = zi[64 + idx];
            s00 += r0.x*r0.x + r0.y*r0.y + r0.z*r0.z + r0.w*r0.w;
            s11 += r1.x*r1.x + r1.y*r1.y + r1.z*r1.z + r1.w*r1.w;
            s22 += r2.x*r2.x + r2.y*r2.y + r2.z*r2.z + r2.w*r2.w;
            s33 += r3.x*r3.x + r3.y*r3.y + r3.z*r3.z + r3.w*r3.w;
            s01 += r0.x*r1.x + r0.y*r1.y + r0.z*r1.z + r0.w*r1.w;
            s02 += r0.x*r2.x + r0.y*r2.y + r0.z*r2.z + r0.w*r2.w;
            s03 += r0.x*r3.x + r0.y*r3.y + r0.z*r3.z + r0.w*r3.w;
            s12 += r1.x*r2.x + r1.y*r2.y + r1.z*r2.z + r1.w*r2.w;
            s13 += r1.x*r3.x + r1.y*r3.y + r1.z*r3.z + r1.w*r3.w;
            s23 += r2.x*r3.x + r2.y*r3.y + r2.z*r3.z + r2.w*r3.w;
        }

        // butterfly reduce across the 16-lane group (xor masks < 16 stay in-group)
        #pragma unroll
        for (int m = 1; m < 16; m <<= 1) {
            s00 += __shfl_xor(s00, m);
            s11 += __shfl_xor(s11, m);
            s22 += __shfl_xor(s22, m);
            s33 += __shfl_xor(s33, m);
            s01 += __shfl_xor(s01, m);
            s02 += __shfl_xor(s02, m);
            s03 += __shfl_xor(s03, m);
            s12 += __shfl_xor(s12, m);
            s13 += __shfl_xor(s13, m);
            s23 += __shfl_xor(s23, m);
        }

        if (lane == 0) {
            float i0 = 1.0f / fmaxf(sqrtf(s00), EPS);
            float i1 = 1.0f / fmaxf(sqrtf(s11), EPS);
            float i2 = 1.0f / fmaxf(sqrtf(s22), EPS);
            float i3 = 1.0f / fmaxf(sqrtf(s33), EPS);
            float v01 = s01 * i0 * i1;
            float v02 = s02 * i0 * i2;
            float v03 = s03 * i0 * i3;
            float v12 = s12 * i1 * i2;
            float v13 = s13 * i1 * i3;
            float v23 = s23 * i2 * i3;
            // rows: pos / negs per NEG_IDX = [[1,3],[0,2],[1,3],[0,2]]
            local += row_loss(v02, v01, v03)
                   + row_loss(v13, v01, v12)
                   + row_loss(v02, v12, v23)
                   + row_loss(v13, v03, v23);
        }
    }

    // block reduction: wave64 butterfly, then tiny LDS combine
    #pragma unroll
    for (int m = 1; m < 64; m <<= 1) local += __shfl_xor(local, m);
    __shared__ float red[4];
    if ((threadIdx.x & 63) == 0) red[threadIdx.x >> 6] = local;
    __syncthreads();
    if (threadIdx.x == 0) partial[blockIdx.x] = red[0] + red[1] + red[2] + red[3];
}

__global__ __launch_bounds__(256) void ntxent_final_kernel(
    const float* __restrict__ partial, int nb, float* __restrict__ out, float scale)
{
    float v = 0.0f;
    for (int i = threadIdx.x; i < nb; i += 256) v += partial[i];
    #pragma unroll
    for (int m = 1; m < 64; m <<= 1) v += __shfl_xor(v, m);
    __shared__ float red[4];
    if ((threadIdx.x & 63) == 0) red[threadIdx.x >> 6] = v;
    __syncthreads();
    if (threadIdx.x == 0) out[0] = (red[0] + red[1] + red[2] + red[3]) * scale;
}

extern "C" void kernel_launch(void* const* d_in, const int* in_sizes, int n_in,
                              void* d_out, int out_size, void* d_ws, size_t ws_size,
                              hipStream_t stream) {
    const float* zis = (const float*)d_in[0];
    const float* zjs = (const float*)d_in[1];
    float* out       = (float*)d_out;
    float* partial   = (float*)d_ws;

    const int B        = in_sizes[0] / D;   // 65536 rows
    const int n_chunks = B / 2;             // 32768 chunks

    int nb = 2048;                          // 2048 blocks x 256 thr = 32768 groups of 16
    size_t cap = ws_size / sizeof(float);
    if (cap < (size_t)nb) nb = (int)(cap > 0 ? cap : 1);

    ntxent_partial_kernel<<<nb, 256, 0, stream>>>(zis, zjs, n_chunks, partial);
    ntxent_final_kernel<<<1, 256, 0, stream>>>(partial, nb, out, 1.0f / (float)B);
}

// Round 2
// 28.971 us; speedup vs baseline: 1.1632x; 1.1632x over previous
//
#include <hip/hip_runtime.h>
#include <math.h>

#define D 256
#define EPS 1e-8f

// loss of one row: logits = {pos, n1, n2} / 0.5, CE with label 0
__device__ __forceinline__ float row_loss(float pos, float na, float nb) {
    float l0 = pos + pos;   // /T with T=0.5
    float l1 = na + na;
    float l2 = nb + nb;
    float m  = fmaxf(l0, fmaxf(l1, l2));
    float e  = expf(l0 - m) + expf(l1 - m) + expf(l2 - m);
    return logf(e) - (l0 - m);
}

// 8 lanes per chunk. Per lane: 32 independent float4 loads (4 rows x 8),
// 10 partial sums, 3-step butterfly (30 shuffles per wave covering 8 chunks),
// then lanes r=0..3 of each group each compute one row's loss in parallel.
__global__ __launch_bounds__(256) void ntxent_partial_kernel(
    const float* __restrict__ zis, const float* __restrict__ zjs,
    int n_chunks, float* __restrict__ partial)
{
    const int tid      = blockIdx.x * 256 + threadIdx.x;
    const int lane8    = threadIdx.x & 7;           // lane within 8-lane group
    const int group    = tid >> 3;
    const int n_groups = (gridDim.x * 256) >> 3;

    float local = 0.0f;

    for (int c = group; c < n_chunks; c += n_groups) {
        // reps rows: r0 = zj row0, r1 = zj row1, r2 = zi row0, r3 = zi row1
        const float4* zi = (const float4*)(zis + (size_t)c * (2 * D));
        const float4* zj = (const float4*)(zjs + (size_t)c * (2 * D));

        float s00=0.f,s11=0.f,s22=0.f,s33=0.f;
        float s01=0.f,s02=0.f,s03=0.f,s12=0.f,s13=0.f,s23=0.f;
        #pragma unroll
        for (int j = 0; j < 8; ++j) {
            const int idx = lane8 + 8 * j;          // float4 index within 64-float4 row
            float4 r0 = zj[idx];
            float4 r1 = zj[64 + idx];
            float4 r2 = zi[idx];
            float4 r3 = zi[64 + idx];
            s00 += r0.x*r0.x + r0.y*r0.y + r0.z*r0.z + r0.w*r0.w;
            s11 += r1.x*r1.x + r1.y*r1.y + r1.z*r1.z + r1.w*r1.w;
            s22 += r2.x*r2.x + r2.y*r2.y + r2.z*r2.z + r2.w*r2.w;
            s33 += r3.x*r3.x + r3.y*r3.y + r3.z*r3.z + r3.w*r3.w;
            s01 += r0.x*r1.x + r0.y*r1.y + r0.z*r1.z + r0.w*r1.w;
            s02 += r0.x*r2.x + r0.y*r2.y + r0.z*r2.z + r0.w*r2.w;
            s03 += r0.x*r3.x + r0.y*r3.y + r0.z*r3.z + r0.w*r3.w;
            s12 += r1.x*r2.x + r1.y*r2.y + r1.z*r2.z + r1.w*r2.w;
            s13 += r1.x*r3.x + r1.y*r3.y + r1.z*r3.z + r1.w*r3.w;
            s23 += r2.x*r3.x + r2.y*r3.y + r2.z*r3.z + r2.w*r3.w;
        }

        // butterfly reduce across the 8-lane group; every lane ends with totals
        #pragma unroll
        for (int m = 1; m < 8; m <<= 1) {
            s00 += __shfl_xor(s00, m);
            s11 += __shfl_xor(s11, m);
            s22 += __shfl_xor(s22, m);
            s33 += __shfl_xor(s33, m);
            s01 += __shfl_xor(s01, m);
            s02 += __shfl_xor(s02, m);
            s03 += __shfl_xor(s03, m);
            s12 += __shfl_xor(s12, m);
            s13 += __shfl_xor(s13, m);
            s23 += __shfl_xor(s23, m);
        }

        // lanes 0..3 each compute one row's loss (rows per NEG_IDX):
        //   row0: pos=v02 negs v01,v03 | row1: pos=v13 negs v01,v12
        //   row2: pos=v02 negs v12,v23 | row3: pos=v13 negs v03,v23
        float rl = 0.0f;
        if (lane8 < 4) {
            const int r = lane8;
            float i0 = 1.0f / fmaxf(sqrtf(s00), EPS);
            float i1 = 1.0f / fmaxf(sqrtf(s11), EPS);
            float i2 = 1.0f / fmaxf(sqrtf(s22), EPS);
            float i3 = 1.0f / fmaxf(sqrtf(s33), EPS);
            float v01 = s01 * i0 * i1;
            float v02 = s02 * i0 * i2;
            float v03 = s03 * i0 * i3;
            float v12 = s12 * i1 * i2;
            float v13 = s13 * i1 * i3;
            float v23 = s23 * i2 * i3;
            float pos = (r & 1) ? v13 : v02;
            float na  = (r < 2) ? v01 : ((r == 2) ? v12 : v03);
            float nb  = (r == 0) ? v03 : ((r == 1) ? v12 : v23);
            rl = row_loss(pos, na, nb);
        }
        // fold the 4 row losses (xor 1,2 stays within lanes 0-3 / 4-7)
        rl += __shfl_xor(rl, 1);
        rl += __shfl_xor(rl, 2);
        if (lane8 == 0) local += rl;
    }

    // block reduction: wave64 butterfly, then tiny LDS combine
    #pragma unroll
    for (int m = 1; m < 64; m <<= 1) local += __shfl_xor(local, m);
    __shared__ float red[4];
    if ((threadIdx.x & 63) == 0) red[threadIdx.x >> 6] = local;
    __syncthreads();
    if (threadIdx.x == 0) partial[blockIdx.x] = red[0] + red[1] + red[2] + red[3];
}

__global__ __launch_bounds__(256) void ntxent_final_kernel(
    const float* __restrict__ partial, int nb, float* __restrict__ out, float scale)
{
    float v = 0.0f;
    for (int i = threadIdx.x; i < nb; i += 256) v += partial[i];
    #pragma unroll
    for (int m = 1; m < 64; m <<= 1) v += __shfl_xor(v, m);
    __shared__ float red[4];
    if ((threadIdx.x & 63) == 0) red[threadIdx.x >> 6] = v;
    __syncthreads();
    if (threadIdx.x == 0) out[0] = (red[0] + red[1] + red[2] + red[3]) * scale;
}

extern "C" void kernel_launch(void* const* d_in, const int* in_sizes, int n_in,
                              void* d_out, int out_size, void* d_ws, size_t ws_size,
                              hipStream_t stream) {
    const float* zis = (const float*)d_in[0];
    const float* zjs = (const float*)d_in[1];
    float* out       = (float*)d_out;
    float* partial   = (float*)d_ws;

    const int B        = in_sizes[0] / D;   // 65536 rows
    const int n_chunks = B / 2;             // 32768 chunks

    int nb = 1024;                          // 1024 blocks x 256 thr = 32768 groups of 8
    size_t cap = ws_size / sizeof(float);
    if (cap < (size_t)nb) nb = (int)(cap > 0 ? cap : 1);

    ntxent_partial_kernel<<<nb, 256, 0, stream>>>(zis, zjs, n_chunks, partial);
    ntxent_final_kernel<<<1, 256, 0, stream>>>(partial, nb, out, 1.0f / (float)B);
}